// Round 1
// baseline (165.516 us; speedup 1.0000x reference)
//
#include <hip/hip_runtime.h>
#include <hip/hip_cooperative_groups.h>
#include <cmath>

namespace cg = cooperative_groups;

// SoftmaxStable over N = 2^26 fp32 (256 MiB in, 256 MiB out).
// FUSED cooperative kernel: 512 blocks x 256 thr (2 blocks/CU, <=256 VGPR).
//  Phase 1a: each thread holds 40 float4 (160 VGPRs) of region A (80 MiB),
//            max-then-expf-sum in registers.
//  Phase 1b: stream region B (176 MiB, < L3) in groups of 8 float4,
//            combine (m, s) partials. B is the MRU content of L3 at sync.
//  grid.sync(); every block redundantly reduces the 512 partials (determin.).
//  Phase 3a: re-read B (L3-resident hope) -> out, non-temporal stores.
//  Phase 3b: out for A straight from registers (zero re-read).
// HBM floor: 256 rd + 256 wr = 512 MiB ~ 85 us. Guaranteed saving: A (80 MiB).
// Falls back to the verified 3-kernel path if cooperative launch unavailable.

typedef float f4v __attribute__((ext_vector_type(4)));

#define BLOCK 256
#define HELD  40        // float4 held in registers per thread (160 VGPRs)
#define GMAX  512       // 2 blocks/CU * 256 CU co-resident

// fallback (previous verified kernel) config
#define NBLK  8192
#define ITERS 8

// Combine two (max, sum) states; fp32 __expf scale, fp64 sum.
__device__ __forceinline__ void combine(float& m, double& s, float m2, double s2) {
    float mn = fmaxf(m, m2);
    double e1 = (m  == mn) ? s  : s  * (double)__expf(m  - mn);
    double e2 = (m2 == mn) ? s2 : s2 * (double)__expf(m2 - mn);
    s = e1 + e2;
    m = mn;
}

__global__ __launch_bounds__(BLOCK, 2)
void k_fused(const f4v* __restrict__ x, f4v* __restrict__ o, long n4,
             double* __restrict__ ps, float* __restrict__ pm) {
    const int  G = gridDim.x;
    const long T = (long)G * BLOCK;

    // ---------- phase 1a: held region A, block-contiguous ----------
    const long hbase = (long)blockIdx.x * (BLOCK * HELD) + threadIdx.x;
    f4v hv[HELD];
#pragma unroll
    for (int j = 0; j < HELD; ++j) hv[j] = x[hbase + (long)j * BLOCK];

    float m = -INFINITY;
#pragma unroll
    for (int j = 0; j < HELD; ++j)
        m = fmaxf(m, fmaxf(fmaxf(hv[j].x, hv[j].y), fmaxf(hv[j].z, hv[j].w)));
    float s0 = 0.f;
#pragma unroll
    for (int j = 0; j < HELD; ++j)
        s0 += __expf(hv[j].x - m) + __expf(hv[j].y - m)
            + __expf(hv[j].z - m) + __expf(hv[j].w - m);
    double sd = (double)s0;

    // ---------- phase 1b: remainder region B, groups of 8 float4 ----------
    const long R0   = T * HELD;             // f4 index where B starts
    const long r4   = (n4 - R0) / T;        // f4 per thread (exact for pow2 G)
    const int  ngrp = (int)(r4 >> 3);
    const long rbase = R0 + (long)blockIdx.x * (BLOCK * r4) + threadIdx.x;
    for (int g = 0; g < ngrp; ++g) {
        f4v tv[8];
        const long gb = rbase + (long)g * (BLOCK * 8);
#pragma unroll
        for (int j = 0; j < 8; ++j) tv[j] = x[gb + (long)j * BLOCK];
        float mg = -INFINITY;
#pragma unroll
        for (int j = 0; j < 8; ++j)
            mg = fmaxf(mg, fmaxf(fmaxf(tv[j].x, tv[j].y), fmaxf(tv[j].z, tv[j].w)));
        float sg = 0.f;
#pragma unroll
        for (int j = 0; j < 8; ++j)
            sg += __expf(tv[j].x - mg) + __expf(tv[j].y - mg)
                + __expf(tv[j].z - mg) + __expf(tv[j].w - mg);
        combine(m, sd, mg, (double)sg);
    }

    // ---------- block reduce -> per-block partial ----------
    for (int off = 32; off > 0; off >>= 1) {
        float  m2 = __shfl_down(m,  off, 64);
        double s2 = __shfl_down(sd, off, 64);
        combine(m, sd, m2, s2);
    }
    __shared__ float  sm[BLOCK / 64];
    __shared__ double ss[BLOCK / 64];
    const int lane = threadIdx.x & 63;
    const int wid  = threadIdx.x >> 6;
    if (lane == 0) { sm[wid] = m; ss[wid] = sd; }
    __syncthreads();
    if (threadIdx.x == 0) {
        for (int w = 1; w < BLOCK / 64; ++w) combine(m, sd, sm[w], ss[w]);
        ps[blockIdx.x] = sd;
        pm[blockIdx.x] = m;
    }
    __threadfence();          // device-scope visibility of partials
    cg::this_grid().sync();

    // ---------- every block reduces all G partials (redundant, determ.) ----
    float  mf = -INFINITY;
    double sf = 0.0;
    for (int i = threadIdx.x; i < G; i += BLOCK) combine(mf, sf, pm[i], ps[i]);
    for (int off = 32; off > 0; off >>= 1) {
        float  m2 = __shfl_down(mf, off, 64);
        double s2 = __shfl_down(sf, off, 64);
        combine(mf, sf, m2, s2);
    }
    if (lane == 0) { sm[wid] = mf; ss[wid] = sf; }
    __syncthreads();
    __shared__ float fm, fi;
    if (threadIdx.x == 0) {
        for (int w = 1; w < BLOCK / 64; ++w) combine(mf, sf, sm[w], ss[w]);
        fm = mf;
        fi = (float)(1.0 / sf);
    }
    __syncthreads();
    const float M   = fm;
    const float INV = fi;

    // ---------- phase 3a: remainder B first (re-read while L3-hot) --------
    for (int g = 0; g < ngrp; ++g) {
        f4v tv[8];
        const long gb = rbase + (long)g * (BLOCK * 8);
#pragma unroll
        for (int j = 0; j < 8; ++j) tv[j] = x[gb + (long)j * BLOCK];
#pragma unroll
        for (int j = 0; j < 8; ++j) {
            f4v r;
            r.x = __expf(tv[j].x - M) * INV;
            r.y = __expf(tv[j].y - M) * INV;
            r.z = __expf(tv[j].z - M) * INV;
            r.w = __expf(tv[j].w - M) * INV;
            __builtin_nontemporal_store(r, &o[gb + (long)j * BLOCK]);
        }
    }
    // ---------- phase 3b: held region A straight from registers -----------
#pragma unroll
    for (int j = 0; j < HELD; ++j) {
        f4v r;
        r.x = __expf(hv[j].x - M) * INV;
        r.y = __expf(hv[j].y - M) * INV;
        r.z = __expf(hv[j].z - M) * INV;
        r.w = __expf(hv[j].w - M) * INV;
        __builtin_nontemporal_store(r, &o[hbase + (long)j * BLOCK]);
    }
}

// ======================= fallback: verified 3-kernel path ==================

__global__ __launch_bounds__(BLOCK)
void k_partials(const f4v* __restrict__ x, long n4,
                double* __restrict__ ps, float* __restrict__ pm) {
    long base = (long)blockIdx.x * (BLOCK * ITERS) + threadIdx.x;
    f4v v[ITERS];
#pragma unroll
    for (int j = 0; j < ITERS; ++j) {
        long idx = base + (long)j * BLOCK;
        if (idx < n4) v[j] = x[idx];
        else          v[j] = (f4v){-INFINITY, -INFINITY, -INFINITY, -INFINITY};
    }
    float m = -INFINITY;
#pragma unroll
    for (int j = 0; j < ITERS; ++j)
        m = fmaxf(m, fmaxf(fmaxf(v[j].x, v[j].y), fmaxf(v[j].z, v[j].w)));
    float s = 0.f;
    if (m != -INFINITY) {
#pragma unroll
        for (int j = 0; j < ITERS; ++j)
            s += __expf(v[j].x - m) + __expf(v[j].y - m) +
                 __expf(v[j].z - m) + __expf(v[j].w - m);
    }
    double sd = (double)s;
    for (int off = 32; off > 0; off >>= 1) {
        float  m2 = __shfl_down(m,  off, 64);
        double s2 = __shfl_down(sd, off, 64);
        combine(m, sd, m2, s2);
    }
    __shared__ float  sm[BLOCK / 64];
    __shared__ double ss[BLOCK / 64];
    int lane = threadIdx.x & 63;
    int wid  = threadIdx.x >> 6;
    if (lane == 0) { sm[wid] = m; ss[wid] = sd; }
    __syncthreads();
    if (threadIdx.x == 0) {
        for (int w = 1; w < BLOCK / 64; ++w) combine(m, sd, sm[w], ss[w]);
        ps[blockIdx.x] = sd;
        pm[blockIdx.x] = m;
    }
}

__global__ __launch_bounds__(1024)
void k_reduce(const double* __restrict__ ps, const float* __restrict__ pm,
              int nblk, float* __restrict__ fin) {
    float  m = -INFINITY;
    double s = 0.0;
    for (int i = threadIdx.x; i < nblk; i += 1024) combine(m, s, pm[i], ps[i]);
    for (int off = 32; off > 0; off >>= 1) {
        float  m2 = __shfl_down(m, off, 64);
        double s2 = __shfl_down(s, off, 64);
        combine(m, s, m2, s2);
    }
    __shared__ float  sm[16];
    __shared__ double ss[16];
    int lane = threadIdx.x & 63;
    int wid  = threadIdx.x >> 6;
    if (lane == 0) { sm[wid] = m; ss[wid] = s; }
    __syncthreads();
    if (threadIdx.x == 0) {
        for (int w = 1; w < 16; ++w) combine(m, s, sm[w], ss[w]);
        fin[0] = m;
        fin[1] = (float)(1.0 / s);
    }
}

__global__ __launch_bounds__(BLOCK)
void k_out(const f4v* __restrict__ x, f4v* __restrict__ o, long n4,
           const float* __restrict__ fin) {
    float m   = fin[0];
    float inv = fin[1];
    long stride = (long)gridDim.x * BLOCK;
    for (long i = (long)blockIdx.x * BLOCK + threadIdx.x; i < n4; i += stride) {
        f4v v = x[i];
        f4v r;
        r.x = __expf(v.x - m) * inv;
        r.y = __expf(v.y - m) * inv;
        r.z = __expf(v.z - m) * inv;
        r.w = __expf(v.w - m) * inv;
        __builtin_nontemporal_store(r, &o[i]);
    }
}

extern "C" void kernel_launch(void* const* d_in, const int* in_sizes, int n_in,
                              void* d_out, int out_size, void* d_ws, size_t ws_size,
                              hipStream_t stream) {
    const f4v* x = (const f4v*)d_in[0];
    f4v* out = (f4v*)d_out;
    long n  = (long)in_sizes[0];
    long n4 = n / 4;                 // N = 2^26, exactly divisible

    // ws layout: [NBLK doubles: s partials][NBLK floats: m partials][2 floats]
    double* ps  = (double*)d_ws;
    float*  pm  = (float*)((char*)d_ws + NBLK * sizeof(double));
    float*  fin = (float*)((char*)d_ws + NBLK * (sizeof(double) + sizeof(float)));

    // One-time: clamp cooperative grid to co-resident capacity (pow2 so the
    // per-thread work division stays exact). 0 => use fallback path.
    static int g_grid = -1;
    if (g_grid < 0) {
        int nb = 0;
        if (hipOccupancyMaxActiveBlocksPerMultiprocessor(&nb, k_fused, BLOCK, 0)
                != hipSuccess) nb = 0;
        int dev = 0;
        (void)hipGetDevice(&dev);
        hipDeviceProp_t prop{};
        int cus = 256;
        if (hipGetDeviceProperties(&prop, dev) == hipSuccess && prop.multiProcessorCount > 0)
            cus = prop.multiProcessorCount;
        long cap = (long)nb * cus;
        if (cap >= 1) {
            int g = GMAX;
            while (g > 1 && g > cap) g >>= 1;
            g_grid = g;
        } else {
            g_grid = 0;
        }
    }

    bool done = false;
    if (g_grid > 0) {
        void* args[] = { (void*)&x, (void*)&out, (void*)&n4, (void*)&ps, (void*)&pm };
        hipError_t err = hipLaunchCooperativeKernel((void*)k_fused, dim3(g_grid),
                                                    dim3(BLOCK), args, 0, stream);
        if (err == hipSuccess) {
            done = true;
        } else {
            (void)hipGetLastError();   // clear sticky error, use fallback forever
            g_grid = 0;
        }
    }

    if (!done) {
        hipLaunchKernelGGL(k_partials, dim3(NBLK), dim3(BLOCK), 0, stream,
                           x, n4, ps, pm);
        hipLaunchKernelGGL(k_reduce, dim3(1), dim3(1024), 0, stream, ps, pm, NBLK, fin);
        hipLaunchKernelGGL(k_out, dim3(NBLK), dim3(BLOCK), 0, stream,
                           x, out, n4, fin);
    }
}

// Round 2
// 130.591 us; speedup vs baseline: 1.2674x; 1.2674x over previous
//
#include <hip/hip_runtime.h>
#include <cmath>

// SoftmaxStable over N = 2^26 fp32 elements (256 MiB in, 256 MiB out).
//
// 3-kernel structure (saturates HBM at 32 waves/CU) + L3 residency engineering:
//  Pass 1 (k_partials): per-block (m, s) partials. The FIRST 64 MiB of x is
//    loaded NON-TEMPORALLY (no L3 allocate); the last 192 MiB loads normally,
//    leaving L3 holding the tail of x with 64 MiB slack (round-1 counters
//    proved a sub-capacity MRU set survives and serves re-reads: FETCH 226 MB
//    vs 432 MB compulsory+re-read in the fused experiment).
//  Pass 2 (k_reduce): 8192 partials -> (m, 1/total).
//  Pass 3 (k_out): out = __expf(x-m)*inv, sweeping x TAIL-FIRST so the first
//    re-reads hit the freshest L3 lines; head 64 MiB read last (honest miss).
//    Non-temporal stores (round 1: nt stores do not evict the resident set).
//
// Traffic target: 256 rd + ~64-100 rd + 256 wr  ~=  590-620 MB  ->  ~100 us.

typedef float f4v __attribute__((ext_vector_type(4)));

#define BLOCK 256
#define NBLK  8192        // 8192 blk * 256 thr * 8 f4 = 2^26 elems exactly
#define ITERS 8
#define NT_HEAD_BLKS (NBLK / 4)   // first 64 MiB: non-temporal pass-1 loads

// Combine two (max, sum) states; scale factor via fp32 __expf, sum in fp64.
// Guards m==mn so (-inf,-inf) never produces 0*inf or exp(nan).
__device__ __forceinline__ void combine(float& m, double& s, float m2, double s2) {
    float mn = fmaxf(m, m2);
    double e1 = (m  == mn) ? s  : s  * (double)__expf(m  - mn);
    double e2 = (m2 == mn) ? s2 : s2 * (double)__expf(m2 - mn);
    s = e1 + e2;
    m = mn;
}

__global__ __launch_bounds__(BLOCK)
void k_partials(const f4v* __restrict__ x, long n4,
                double* __restrict__ ps, float* __restrict__ pm) {
    // Block-contiguous chunk: 8 iters * 256 thr * 16B = 32 KB per block.
    long base = (long)blockIdx.x * (BLOCK * ITERS) + threadIdx.x;
    f4v v[ITERS];
    if (blockIdx.x < NT_HEAD_BLKS) {
        // Head region: stream through without allocating in L3.
#pragma unroll
        for (int j = 0; j < ITERS; ++j) {
            long idx = base + (long)j * BLOCK;
            if (idx < n4) v[j] = __builtin_nontemporal_load(&x[idx]);
            else          v[j] = (f4v){-INFINITY, -INFINITY, -INFINITY, -INFINITY};
        }
    } else {
        // Tail region: normal loads -> L3-resident for pass 3.
#pragma unroll
        for (int j = 0; j < ITERS; ++j) {
            long idx = base + (long)j * BLOCK;
            if (idx < n4) v[j] = x[idx];
            else          v[j] = (f4v){-INFINITY, -INFINITY, -INFINITY, -INFINITY};
        }
    }
    float m = -INFINITY;
#pragma unroll
    for (int j = 0; j < ITERS; ++j)
        m = fmaxf(m, fmaxf(fmaxf(v[j].x, v[j].y), fmaxf(v[j].z, v[j].w)));
    float s = 0.f;
    if (m != -INFINITY) {   // all-padding thread guard (never taken at N=2^26)
#pragma unroll
        for (int j = 0; j < ITERS; ++j)
            s += __expf(v[j].x - m) + __expf(v[j].y - m) +
                 __expf(v[j].z - m) + __expf(v[j].w - m);
    }
    double sd = (double)s;
    for (int off = 32; off > 0; off >>= 1) {   // 64-lane wave butterfly
        float  m2 = __shfl_down(m,  off, 64);
        double s2 = __shfl_down(sd, off, 64);
        combine(m, sd, m2, s2);
    }
    __shared__ float  sm[BLOCK / 64];
    __shared__ double ss[BLOCK / 64];
    int lane = threadIdx.x & 63;
    int wid  = threadIdx.x >> 6;
    if (lane == 0) { sm[wid] = m; ss[wid] = sd; }
    __syncthreads();
    if (threadIdx.x == 0) {
        for (int w = 1; w < BLOCK / 64; ++w) combine(m, sd, sm[w], ss[w]);
        ps[blockIdx.x] = sd;
        pm[blockIdx.x] = m;
    }
}

__global__ __launch_bounds__(1024)
void k_reduce(const double* __restrict__ ps, const float* __restrict__ pm,
              int nblk, float* __restrict__ fin) {
    float  m = -INFINITY;
    double s = 0.0;
    for (int i = threadIdx.x; i < nblk; i += 1024) combine(m, s, pm[i], ps[i]);
    for (int off = 32; off > 0; off >>= 1) {
        float  m2 = __shfl_down(m, off, 64);
        double s2 = __shfl_down(s, off, 64);
        combine(m, s, m2, s2);
    }
    __shared__ float  sm[16];
    __shared__ double ss[16];
    int lane = threadIdx.x & 63;
    int wid  = threadIdx.x >> 6;
    if (lane == 0) { sm[wid] = m; ss[wid] = s; }
    __syncthreads();
    if (threadIdx.x == 0) {
        for (int w = 1; w < 16; ++w) combine(m, s, sm[w], ss[w]);
        fin[0] = m;
        fin[1] = (float)(1.0 / s);   // reciprocal in fp64, cast once
    }
}

__global__ __launch_bounds__(BLOCK)
void k_out(const f4v* __restrict__ x, f4v* __restrict__ o, long n4,
           const float* __restrict__ fin) {
    float m   = fin[0];   // wave-uniform
    float inv = fin[1];
    long stride = (long)gridDim.x * BLOCK;       // f4 per sweep
    long nswp = (n4 + stride - 1) / stride;      // = 8 at this size
    // TAIL-FIRST: sweep from the end of x (freshest in L3 after pass 1)
    // toward the head (nt-loaded in pass 1, honest HBM miss, read last).
    for (long sw = nswp - 1; sw >= 0; --sw) {
        long i = sw * stride + (long)blockIdx.x * BLOCK + threadIdx.x;
        if (i < n4) {
            f4v v = x[i];     // normal load: want the L3 hit
            f4v r;
            r.x = __expf(v.x - m) * inv;
            r.y = __expf(v.y - m) * inv;
            r.z = __expf(v.z - m) * inv;
            r.w = __expf(v.w - m) * inv;
            __builtin_nontemporal_store(r, &o[i]);   // don't evict x from L3
        }
    }
}

extern "C" void kernel_launch(void* const* d_in, const int* in_sizes, int n_in,
                              void* d_out, int out_size, void* d_ws, size_t ws_size,
                              hipStream_t stream) {
    const float* x = (const float*)d_in[0];
    float* out = (float*)d_out;
    long n  = (long)in_sizes[0];
    long n4 = n / 4;                // N = 2^26, exactly divisible

    // ws layout: [NBLK doubles: s partials][NBLK floats: m partials][2 floats]
    double* ps  = (double*)d_ws;
    float*  pm  = (float*)((char*)d_ws + NBLK * sizeof(double));
    float*  fin = (float*)((char*)d_ws + NBLK * (sizeof(double) + sizeof(float)));

    hipLaunchKernelGGL(k_partials, dim3(NBLK), dim3(BLOCK), 0, stream,
                       (const f4v*)x, n4, ps, pm);
    hipLaunchKernelGGL(k_reduce, dim3(1), dim3(1024), 0, stream, ps, pm, NBLK, fin);
    hipLaunchKernelGGL(k_out, dim3(NBLK), dim3(BLOCK), 0, stream,
                       (const f4v*)x, (f4v*)out, n4, fin);
}